// Round 4
// baseline (672.376 us; speedup 1.0000x reference)
//
#include <hip/hip_runtime.h>
#include <stdint.h>

#define NN 64
#define CC 128
#define TT 300
#define VV 25
#define TV 7500
#define DD 256
#define RR 32
#define JPAD 7552   // 59*128 padded j-rows (y) and z row stride

// ws float offsets
#define OFF_S1P    0          // [c][64] partial x sums
#define OFF_SS1P   8192       // [c][64] partial x sumsq
#define OFF_PS     16384      // [n][c] xs sums
#define OFF_A1     24576
#define OFF_B1     24704
#define OFF_SUM2   24832
#define OFF_SUMSQ2 25088
#define OFF_A2     25344
#define OFF_B2     25600
#define OFF_GATE   25856
#define OFF_BIAS2  26112      // [n][d] 16384
#define OFF_CORR0  42496      // [n][d] 16384
#define OFF_CORR9  58880      // [n][d] 16384
#define FLOAT_REGION 75264
#define ZERO_CNT   25344      // S1P..SUMSQ2
#define WT_BYTE_OFF ((size_t)FLOAT_REGION * 4)
#define WT_BYTES    ((size_t)NN * DD * CC * 2)
#define Z_BYTE_OFF  (WT_BYTE_OFF + WT_BYTES)

typedef __attribute__((ext_vector_type(8))) short short8;
typedef __attribute__((ext_vector_type(4))) float f32x4;

typedef const __attribute__((address_space(1))) uint32_t gas_u32;
typedef __attribute__((address_space(3))) uint32_t las_u32;

__device__ inline ushort f2bf(float f) {
    uint32_t u = __float_as_uint(f);
    u += 0x7fffu + ((u >> 16) & 1u);
    return (ushort)(u >> 16);
}
__device__ inline float bf2f(ushort v) { return __uint_as_float(((uint32_t)v) << 16); }
__device__ inline void async_copy16(const void* g, void* l) {
    __builtin_amdgcn_global_load_lds((gas_u32*)g, (las_u32*)l, 16, 0, 0);
}

__device__ inline void block_reduce2(float& a, float& b) {
    __shared__ float sa[4], sb[4];
    for (int off = 32; off > 0; off >>= 1) {
        a += __shfl_down(a, off);
        b += __shfl_down(b, off);
    }
    int lane = threadIdx.x & 63, wid = threadIdx.x >> 6;
    if (lane == 0) { sa[wid] = a; sb[wid] = b; }
    __syncthreads();
    if (threadIdx.x == 0) {
        a = sa[0] + sa[1] + sa[2] + sa[3];
        b = sb[0] + sb[1] + sb[2] + sb[3];
    }
}

__global__ void k_zero(float* ws) {
    int i = blockIdx.x * 256 + threadIdx.x;
    for (; i < ZERO_CNT; i += 32 * 256) ws[i] = 0.f;
}

// ONE pass over x: xs = shift(x) -> yT bf16 swizzled; BN1 stats of raw x; xs sums for p.
// grid (118 j-tiles of 64, 64 n).
__global__ __launch_bounds__(256) void k_shift_stats(const float* __restrict__ x,
                                                     const float* __restrict__ shift_in,
                                                     float* __restrict__ ws,
                                                     ushort* __restrict__ yT) {
    __shared__ ushort ytile[CC * 64];   // elem (c, jl) at c*64 + m(c,jl)*8 + (jl&7)
    int jt = blockIdx.x, n = blockIdx.y;
    int j0 = jt * 64;
    int tid = threadIdx.x;
    int jq = tid & 7;
    int cb = tid >> 3;
    for (int ci = 0; ci < 4; ++ci) {
        int c = cb + 32 * ci;
        float sh = shift_in[c];
        bool pos = (sh >= 0.f);
        const float* row = x + (size_t)(n * CC + c) * TV;
        ushort pk[8];
        float psum = 0.f, sx = 0.f, ssx = 0.f;
#pragma unroll
        for (int e = 0; e < 8; ++e) {
            int j = j0 + jq * 8 + e;
            float yv = 0.f, xv = 0.f;
            if (j < TV) {
                int t = j / VV;
                int v = j - t * VV;
                float posf = (float)t + sh;
                float f0 = floorf(posf);
                int i0 = (int)f0;
                float frac = posf - f0;
                int i1 = i0 + 1;
                float w0 = (i0 >= 0 && i0 < TT) ? (1.f - frac) : 0.f;
                float w1 = (i1 >= 0 && i1 < TT) ? frac : 0.f;
                int i0c = min(max(i0, 0), TT - 1), i1c = min(max(i1, 0), TT - 1);
                float x0 = row[i0c * VV + v], x1 = row[i1c * VV + v];
                yv = w0 * x0 + w1 * x1;            // raw shifted x (no BN affine)
                xv = pos ? x0 : x1;                // == x[j] exactly (stats tap)
            }
            psum += yv; sx += xv; ssx += xv * xv;
            pk[e] = f2bf(yv);
        }
        for (int off = 4; off > 0; off >>= 1) {
            psum += __shfl_down(psum, off, 8);
            sx   += __shfl_down(sx, off, 8);
            ssx  += __shfl_down(ssx, off, 8);
        }
        if (jq == 0) {
            atomicAdd(&ws[OFF_PS + n * CC + c], psum);
            atomicAdd(&ws[OFF_S1P + c * 64 + n], sx);
            atomicAdd(&ws[OFF_SS1P + c * 64 + n], ssx);
        }
        uint32_t dw[4];
#pragma unroll
        for (int h = 0; h < 4; ++h) dw[h] = (uint32_t)pk[2 * h] | ((uint32_t)pk[2 * h + 1] << 16);
        int m = jq ^ (c & 7) ^ ((c >> 3) & 7);
        *(uint4*)&ytile[c * 64 + m * 8] = *(uint4*)dw;
    }
    __syncthreads();
    for (int it = 0; it < 4; ++it) {
        int jl = (tid >> 3) + 32 * (it & 1);
        int s  = (tid & 7) + 8 * (it >> 1);
        uint32_t dw[4];
#pragma unroll
        for (int h = 0; h < 4; ++h) {
            int c0 = 8 * s + 2 * h, c1 = c0 + 1;
            int m0 = (jl >> 3) ^ (c0 & 7) ^ (s & 7);
            int m1 = (jl >> 3) ^ (c1 & 7) ^ (s & 7);
            ushort lo = ytile[c0 * 64 + m0 * 8 + (jl & 7)];
            ushort hi = ytile[c1 * 64 + m1 * 8 + (jl & 7)];
            dw[h] = (uint32_t)lo | ((uint32_t)hi << 16);
        }
        int jg = j0 + jl;
        size_t rowb = ((size_t)n * JPAD + jg) * 128;
        *(uint4*)&yT[rowb + (size_t)((s ^ (jg & 7)) << 3)] = *(uint4*)dw;
    }
}

__global__ void k_bn1_final(const float* __restrict__ g1, const float* __restrict__ b1, float* ws) {
    int c = threadIdx.x;
    if (c < CC) {
        float s = 0.f, ss = 0.f;
        for (int g = 0; g < 64; ++g) { s += ws[OFF_S1P + c * 64 + g]; ss += ws[OFF_SS1P + c * 64 + g]; }
        const float inv = 1.f / (float)(NN * TV);
        float m = s * inv;
        float var = ss * inv - m * m;
        float rstd = rsqrtf(var + 1e-5f);
        float A = rstd * g1[c];
        ws[OFF_A1 + c] = A;
        ws[OFF_B1 + c] = b1[c] - m * A;
    }
}

// p -> fc1 -> relu -> fc2 -> softmax(logits/tao). one block.
__global__ void k_gate(const float* __restrict__ fc1_w, const float* __restrict__ fc1_b,
                       const float* __restrict__ fc2_w, const float* __restrict__ fc2_b,
                       const float* __restrict__ shift_in,
                       const int* __restrict__ epoch_p, float* ws) {
    __shared__ float psh[NN][CC];    // 32 KB
    __shared__ float hsh[NN][RR];
    int tid = threadIdx.x;
    const float invTV = 1.f / (float)TV;
    for (int idx = tid; idx < NN * CC; idx += 256) {
        int n = idx >> 7, c = idx & 127;
        float sh = shift_in[c];
        float gb = (sh >= 0.f) ? (1.f - sh) : (1.f + sh);
        float meang = (299.f + gb) * (1.f / 300.f);
        psh[n][c] = ws[OFF_A1 + c] * (ws[OFF_PS + n * CC + c] * invTV) + ws[OFF_B1 + c] * meang;
    }
    __syncthreads();
    int n = tid >> 2;
    int rq = tid & 3;
    for (int r = rq * 8; r < rq * 8 + 8; ++r) {
        float acc = fc1_b[r];
        for (int c = 0; c < CC; ++c) acc += psh[n][c] * fc1_w[r * CC + c];
        hsh[n][r] = fmaxf(acc, 0.f);
    }
    __syncthreads();
    if (tid < NN) {
        int nn = tid;
        int ep = *epoch_p;
        float tao = (ep < 60) ? (-(29.f / 60.f) * (float)ep + 30.f) : 1.f;
        float li[4];
        float mx = -1e30f;
        for (int k = 0; k < 4; ++k) {
            float acc = fc2_b[k];
            for (int r = 0; r < RR; ++r) acc += hsh[nn][r] * fc2_w[k * RR + r];
            li[k] = acc / tao;
            mx = fmaxf(mx, li[k]);
        }
        float se = 0.f;
        for (int k = 0; k < 4; ++k) { li[k] = expf(li[k] - mx); se += li[k]; }
        float inv = 1.f / se;
        for (int k = 0; k < 4; ++k) ws[OFF_GATE + nn * 4 + k] = li[k] * inv;
    }
}

// wT'[n][d][c] = A_c * (sum_k gate tw) bf16 swizzled, plus bias2/corr0/corr299.
// grid 64 (n), 256 threads (d).
__global__ __launch_bounds__(256) void k_wmix(const float* __restrict__ tw, const float* __restrict__ tb,
                                              const float* __restrict__ shift_in,
                                              float* __restrict__ ws, ushort* __restrict__ wT) {
    int n = blockIdx.x, d = threadIdx.x;
    const float* g = &ws[OFF_GATE + n * 4];
    float g0 = g[0], g1 = g[1], g2 = g[2], g3 = g[3];
    float bias2 = g0 * tb[d] + g1 * tb[DD + d] + g2 * tb[2 * DD + d] + g3 * tb[3 * DD + d];
    float c0acc = 0.f, c9acc = 0.f;
    ushort* wrow = wT + ((size_t)n * DD + d) * 128;
    for (int s = 0; s < 16; ++s) {
        uint32_t dw[4];
#pragma unroll
        for (int h = 0; h < 4; ++h) {
            ushort e01[2];
#pragma unroll
            for (int q = 0; q < 2; ++q) {
                int c = s * 8 + 2 * h + q;
                const float* twc = tw + (size_t)c * DD + d;
                float wv = g0 * twc[0] + g1 * twc[32768] + g2 * twc[65536] + g3 * twc[98304];
                float A = ws[OFF_A1 + c], B = ws[OFF_B1 + c];
                float sh = shift_in[c];
                bias2 += B * wv;
                if (sh >= 0.f) c9acc += B * sh * wv; else c0acc += B * (-sh) * wv;
                e01[q] = f2bf(A * wv);
            }
            dw[h] = (uint32_t)e01[0] | ((uint32_t)e01[1] << 16);
        }
        *(uint4*)&wrow[(s ^ (d & 7)) << 3] = *(uint4*)dw;
    }
    ws[OFF_BIAS2 + n * DD + d] = bias2;
    ws[OFF_CORR0 + n * DD + d] = c0acc;
    ws[OFF_CORR9 + n * DD + d] = c9acc;
}

// MFMA GEMM: per (jt, n) stage y once; dt=0,1 re-stages w half. Epilogue adds B-term.
__global__ __launch_bounds__(256) void k_gemm(const ushort* __restrict__ yT,
                                              const ushort* __restrict__ wT,
                                              const float* __restrict__ ws,
                                              ushort* __restrict__ zbuf) {
    __shared__ ushort yl[128 * 128];
    __shared__ ushort wl[128 * 128];
    int jt = blockIdx.x, n = blockIdx.y;
    int tid = threadIdx.x;
    const char* ysrc = (const char*)(yT + ((size_t)n * JPAD + jt * 128) * 128);
#pragma unroll
    for (int i = 0; i < 8; ++i)
        async_copy16(ysrc + (size_t)(i * 256 + tid) * 16, (char*)yl + (i * 256 + tid) * 16);
    int lane = tid & 63;
    int wid = tid >> 6;
    int wm = wid >> 1, wn = wid & 1;
    int l16 = lane & 15, g = lane >> 4;
    bool edge = (jt == 0) || (jt == 58);
    for (int dt = 0; dt < 2; ++dt) {
        const char* wsrc = (const char*)(wT + ((size_t)n * DD + dt * 128) * 128);
        if (dt) __syncthreads();
#pragma unroll
        for (int i = 0; i < 8; ++i)
            async_copy16(wsrc + (size_t)(i * 256 + tid) * 16, (char*)wl + (i * 256 + tid) * 16);
        __syncthreads();
        f32x4 acc[4][4];
#pragma unroll
        for (int a = 0; a < 4; ++a)
#pragma unroll
            for (int b = 0; b < 4; ++b) acc[a][b] = (f32x4)0.f;
#pragma unroll
        for (int ks = 0; ks < 4; ++ks) {
            short8 af[4], bfr[4];
            int chunk = (ks * 4 + g) ^ (l16 & 7);
#pragma unroll
            for (int mi = 0; mi < 4; ++mi)
                af[mi] = *(const short8*)&wl[(wm * 64 + mi * 16 + l16) * 128 + chunk * 8];
#pragma unroll
            for (int ni = 0; ni < 4; ++ni)
                bfr[ni] = *(const short8*)&yl[(wn * 64 + ni * 16 + l16) * 128 + chunk * 8];
#pragma unroll
            for (int mi = 0; mi < 4; ++mi)
#pragma unroll
                for (int ni = 0; ni < 4; ++ni)
                    acc[mi][ni] = __builtin_amdgcn_mfma_f32_16x16x32_bf16(af[mi], bfr[ni], acc[mi][ni], 0, 0, 0);
        }
#pragma unroll
        for (int mi = 0; mi < 4; ++mi) {
#pragma unroll
            for (int r = 0; r < 4; ++r) {
                int d = dt * 128 + wm * 64 + mi * 16 + g * 4 + r;
                float bias = ws[OFF_BIAS2 + n * DD + d];
                float cr0 = 0.f, cr9 = 0.f;
                if (edge) { cr0 = ws[OFF_CORR0 + n * DD + d]; cr9 = ws[OFF_CORR9 + n * DD + d]; }
                size_t zrow = ((size_t)n * DD + d) * JPAD + jt * 128;
#pragma unroll
                for (int ni = 0; ni < 4; ++ni) {
                    int jl = wn * 64 + ni * 16 + l16;
                    float pre = acc[mi][ni][r] + bias;
                    if (edge) {
                        int jg = jt * 128 + jl;
                        if (jg < VV) pre -= cr0;
                        if (jg >= TV - VV) pre -= cr9;
                    }
                    zbuf[zrow + jl] = f2bf(fmaxf(pre, 0.f));
                }
            }
        }
    }
}

// streaming BN2 stats: stage z row in LDS, 2-tap shifted combine, reduce.
__global__ __launch_bounds__(256) void k_bn2_stats(const ushort* __restrict__ zbuf,
                                                   const float* __restrict__ shift_out,
                                                   float* __restrict__ ws) {
    __shared__ ushort zl[JPAD];
    int d = blockIdx.x & 255;
    int n = blockIdx.x >> 8;
    int tid = threadIdx.x;
    const char* zrow = (const char*)(zbuf + ((size_t)n * DD + d) * JPAD);
    for (int k = tid; k < JPAD / 8; k += 256)
        async_copy16(zrow + (size_t)k * 16, (char*)zl + k * 16);
    __syncthreads();
    float sh = shift_out[d];
    float alpha = (sh >= 0.f) ? (1.f - sh) : (-sh);
    float beta  = (sh >= 0.f) ? sh : (1.f + sh);
    int o25 = (sh >= 0.f) ? 0 : -25;
    float s = 0.f, ss = 0.f;
    for (int jj = tid; jj < TV; jj += 256) {
        int i0 = jj + o25, i1 = jj + o25 + 25;
        float z0 = bf2f(zl[max(i0, 0)]);
        float z1 = bf2f(zl[min(i1, TV - 1)]);
        z0 = (i0 >= 0) ? z0 : 0.f;
        z1 = (i1 < TV) ? z1 : 0.f;
        float zs = alpha * z0 + beta * z1;
        s += zs;
        ss += zs * zs;
    }
    block_reduce2(s, ss);
    if (tid == 0) {
        atomicAdd(&ws[OFF_SUM2 + d], s);
        atomicAdd(&ws[OFF_SUMSQ2 + d], ss);
    }
}

__global__ void k_bn2_final(const float* __restrict__ g2, const float* __restrict__ b2, float* ws) {
    int d = threadIdx.x;
    if (d < DD) {
        const float inv = 1.f / (float)(NN * TV);
        float m = ws[OFF_SUM2 + d] * inv;
        float var = ws[OFF_SUMSQ2 + d] * inv - m * m;
        float rstd = rsqrtf(var + 1e-5f);
        float A = rstd * g2[d];
        ws[OFF_A2 + d] = A;
        ws[OFF_B2 + d] = b2[d] - m * A;
    }
}

// out = shifted(z)*A2 + B2, float4 stores.
__global__ __launch_bounds__(256) void k_out(const ushort* __restrict__ zbuf,
                                             const float* __restrict__ shift_out,
                                             const float* __restrict__ ws,
                                             float* __restrict__ out) {
    __shared__ ushort zl[JPAD];
    int d = blockIdx.x & 255;
    int n = blockIdx.x >> 8;
    int tid = threadIdx.x;
    const char* zrow = (const char*)(zbuf + ((size_t)n * DD + d) * JPAD);
    for (int k = tid; k < JPAD / 8; k += 256)
        async_copy16(zrow + (size_t)k * 16, (char*)zl + k * 16);
    __syncthreads();
    float sh = shift_out[d];
    float alpha = (sh >= 0.f) ? (1.f - sh) : (-sh);
    float beta  = (sh >= 0.f) ? sh : (1.f + sh);
    int o25 = (sh >= 0.f) ? 0 : -25;
    float A = ws[OFF_A2 + d], B = ws[OFF_B2 + d];
    float4* orow = (float4*)(out + ((size_t)n * DD + d) * TV);
    for (int k = tid; k < TV / 4; k += 256) {
        int jj = k * 4;
        float4 o4;
        float* op = &o4.x;
#pragma unroll
        for (int q = 0; q < 4; ++q) {
            int i0 = jj + q + o25, i1 = jj + q + o25 + 25;
            float z0 = bf2f(zl[max(i0, 0)]);
            float z1 = bf2f(zl[min(i1, TV - 1)]);
            z0 = (i0 >= 0) ? z0 : 0.f;
            z1 = (i1 < TV) ? z1 : 0.f;
            op[q] = (alpha * z0 + beta * z1) * A + B;
        }
        orow[k] = o4;
    }
}

extern "C" void kernel_launch(void* const* d_in, const int* in_sizes, int n_in,
                              void* d_out, int out_size, void* d_ws, size_t ws_size,
                              hipStream_t stream) {
    const float* x        = (const float*)d_in[0];
    const int*   epoch    = (const int*)d_in[1];
    const float* bn1_g    = (const float*)d_in[2];
    const float* bn1_b    = (const float*)d_in[3];
    const float* bn2_g    = (const float*)d_in[4];
    const float* bn2_b    = (const float*)d_in[5];
    const float* shift_in = (const float*)d_in[6];
    const float* shift_out= (const float*)d_in[7];
    const float* fc1_w    = (const float*)d_in[8];
    const float* fc1_b    = (const float*)d_in[9];
    const float* fc2_w    = (const float*)d_in[10];
    const float* fc2_b    = (const float*)d_in[11];
    const float* tw       = (const float*)d_in[12];
    const float* tb       = (const float*)d_in[13];
    float* out = (float*)d_out;
    float* ws  = (float*)d_ws;
    ushort* yT = (ushort*)d_out;                    // parked in d_out until k_out
    ushort* wT = (ushort*)((char*)d_ws + WT_BYTE_OFF);
    ushort* zb = (ushort*)((char*)d_ws + Z_BYTE_OFF);

    k_zero<<<32, 256, 0, stream>>>(ws);
    k_shift_stats<<<dim3(118, 64), 256, 0, stream>>>(x, shift_in, ws, yT);
    k_bn1_final<<<1, 128, 0, stream>>>(bn1_g, bn1_b, ws);
    k_gate<<<1, 256, 0, stream>>>(fc1_w, fc1_b, fc2_w, fc2_b, shift_in, epoch, ws);
    k_wmix<<<64, 256, 0, stream>>>(tw, tb, shift_in, ws, wT);
    k_gemm<<<dim3(59, 64), 256, 0, stream>>>(yT, wT, ws, zb);
    k_bn2_stats<<<16384, 256, 0, stream>>>(zb, shift_out, ws);
    k_bn2_final<<<1, 256, 0, stream>>>(bn2_g, bn2_b, ws);
    k_out<<<16384, 256, 0, stream>>>(zb, shift_out, ws, out);
}

// Round 5
// 598.889 us; speedup vs baseline: 1.1227x; 1.1227x over previous
//
#include <hip/hip_runtime.h>
#include <stdint.h>

#define NN 64
#define CC 128
#define TT 300
#define VV 25
#define TV 7500
#define DD 256
#define RR 32
#define JPAD 7552   // padded row stride for yT and z (59*128)
#define JT 125      // shift kernel j-tile (exactly 5 t-columns)
#define NJT 60
#define XW 180      // staged x-window floats (7 t rows = 175, +align slack)
#define XSTR 181    // odd LDS stride -> conflict-free gather
#define CBL 64      // c per shift block

// ws float offsets
#define OFF_S1P    0          // [c][64] partial x sums
#define OFF_SS1P   8192       // [c][64] partial x sumsq
#define OFF_PS     16384      // [n][c] xs sums
#define OFF_A1     24576
#define OFF_B1     24704
#define OFF_SUM2   24832
#define OFF_SUMSQ2 25088
#define OFF_A2     25344
#define OFF_B2     25600
#define OFF_GATE   25856
#define OFF_BIAS2  26112      // [n][d]
#define OFF_CORR0  42496      // [n][d]
#define OFF_CORR9  58880      // [n][d]
#define FLOAT_REGION 75264
#define ZERO_CNT   25344
#define WT_BYTE_OFF ((size_t)FLOAT_REGION * 4)
#define WT_BYTES    ((size_t)NN * DD * CC * 2)
#define Z_BYTE_OFF  (WT_BYTE_OFF + WT_BYTES)

typedef __attribute__((ext_vector_type(8))) short short8;
typedef __attribute__((ext_vector_type(4))) float f32x4;

typedef const __attribute__((address_space(1))) uint32_t gas_u32;
typedef __attribute__((address_space(3))) uint32_t las_u32;

__device__ inline ushort f2bf(float f) {
    uint32_t u = __float_as_uint(f);
    u += 0x7fffu + ((u >> 16) & 1u);
    return (ushort)(u >> 16);
}
__device__ inline float bf2f(ushort v) { return __uint_as_float(((uint32_t)v) << 16); }
__device__ inline void async_copy16(const void* g, void* l) {
    __builtin_amdgcn_global_load_lds((gas_u32*)g, (las_u32*)l, 16, 0, 0);
}

__device__ inline void block_reduce2(float& a, float& b) {
    __shared__ float sa[4], sb[4];
    for (int off = 32; off > 0; off >>= 1) {
        a += __shfl_down(a, off);
        b += __shfl_down(b, off);
    }
    int lane = threadIdx.x & 63, wid = threadIdx.x >> 6;
    if (lane == 0) { sa[wid] = a; sb[wid] = b; }
    __syncthreads();
    if (threadIdx.x == 0) {
        a = sa[0] + sa[1] + sa[2] + sa[3];
        b = sb[0] + sb[1] + sb[2] + sb[3];
    }
}

__global__ void k_zero(float* ws) {
    int i = blockIdx.x * 256 + threadIdx.x;
    for (; i < ZERO_CNT; i += 32 * 256) ws[i] = 0.f;
}

// Streaming shift+stats: stage x t-window into LDS, gather from LDS,
// emit yT bf16 (swizzled) + BN1 raw-x stats + p sums.
// grid (60 jt, 2 c-half, 64 n), 256 threads. LDS 62.7 KB -> 2 blocks/CU.
__global__ __launch_bounds__(256) void k_shift_stats(const float* __restrict__ x,
                                                     const float* __restrict__ shift_in,
                                                     float* __restrict__ ws,
                                                     ushort* __restrict__ yT) {
    __shared__ float  xw[CBL * XSTR];     // 46.3 KB
    __shared__ ushort ytile[CBL * 128];   // 16 KB
    int jt = blockIdx.x, ch = blockIdx.y, n = blockIdx.z;
    int j0 = jt * JT;
    int t0 = jt * 5;
    int t_lo = max(t0 - 1, 0);
    int start_f = (t_lo * 25) & ~3;
    int doff = t_lo * 25 - start_f;
    int tid = threadIdx.x;

    // ---- stage: 64 c-windows x 45 float4, coalesced ----
    const float* xbase = x + (size_t)(n * CC + ch * CBL) * TV;
    for (int idx = tid; idx < CBL * 45; idx += 256) {
        int c = idx / 45;
        int q = idx - c * 45;
        int fo = start_f + 4 * q;
        if (fo < TV) {
            float4 u = *(const float4*)(xbase + (size_t)c * TV + fo);
            int o = c * XSTR + 4 * q;
            xw[o] = u.x; xw[o + 1] = u.y; xw[o + 2] = u.z; xw[o + 3] = u.w;
        }
    }
    __syncthreads();

    // ---- gather + stats + pack into ytile ----
    int jq = tid & 7;       // j-chunk of 8
    int cl8 = tid >> 3;     // 0..31
    for (int ci = 0; ci < 2; ++ci) {
        int cl = cl8 + 32 * ci;          // local c 0..63
        int c = ch * CBL + cl;           // global c
        float sh = shift_in[c];
        bool posi = (sh >= 0.f);
        const float* xrow = &xw[cl * XSTR];
        float s_p = 0.f, s_x = 0.f, s_xx = 0.f;
        for (int p = 0; p < 2; ++p) {
            int jb = p * 64 + jq * 8;
            ushort pk[8];
#pragma unroll
            for (int e = 0; e < 8; ++e) {
                int jtl = jb + e;
                float yv = 0.f, xv = 0.f;
                if (jtl < JT) {
                    int j = j0 + jtl;
                    int t = j / VV;
                    int v = j - t * VV;
                    float posf = (float)t + sh;
                    float f0 = floorf(posf);
                    int i0 = (int)f0;
                    float frac = posf - f0;
                    int i1 = i0 + 1;
                    float w0 = (i0 >= 0 && i0 < TT) ? (1.f - frac) : 0.f;
                    float w1 = (i1 >= 0 && i1 < TT) ? frac : 0.f;
                    int i0c = min(max(i0, 0), TT - 1), i1c = min(max(i1, 0), TT - 1);
                    float x0 = xrow[(i0c - t_lo) * VV + v + doff];
                    float x1 = xrow[(i1c - t_lo) * VV + v + doff];
                    yv = w0 * x0 + w1 * x1;
                    xv = posi ? x0 : x1;     // == x[j] exactly
                }
                s_p += yv; s_x += xv; s_xx += xv * xv;
                pk[e] = f2bf(yv);
            }
            uint32_t dw[4];
#pragma unroll
            for (int h = 0; h < 4; ++h) dw[h] = (uint32_t)pk[2 * h] | ((uint32_t)pk[2 * h + 1] << 16);
            int m = p * 8 + (jq ^ (cl & 7) ^ ((cl >> 3) & 7));
            *(uint4*)&ytile[cl * 128 + m * 8] = *(uint4*)dw;
        }
        for (int off = 4; off > 0; off >>= 1) {
            s_p += __shfl_down(s_p, off, 8);
            s_x += __shfl_down(s_x, off, 8);
            s_xx += __shfl_down(s_xx, off, 8);
        }
        if (jq == 0) {
            atomicAdd(&ws[OFF_PS + n * CC + c], s_p);
            atomicAdd(&ws[OFF_S1P + c * 64 + n], s_x);
            atomicAdd(&ws[OFF_SS1P + c * 64 + n], s_xx);
        }
    }
    __syncthreads();

    // ---- transpose read + coalesced global store ----
    for (int it = 0; it < 4; ++it) {
        int idx = it * 256 + tid;
        int s = idx & 7;          // local c-chunk
        int jl = idx >> 3;        // 0..127
        if (jl < JT) {
            int p = jl >> 6, jqv = (jl >> 3) & 7, e = jl & 7;
            uint32_t dw[4];
#pragma unroll
            for (int h = 0; h < 4; ++h) {
                int c0 = 8 * s + 2 * h, c1 = c0 + 1;
                int m0 = p * 8 + (jqv ^ (c0 & 7) ^ s);
                int m1 = p * 8 + (jqv ^ (c1 & 7) ^ s);
                ushort lo = ytile[c0 * 128 + m0 * 8 + e];
                ushort hi = ytile[c1 * 128 + m1 * 8 + e];
                dw[h] = (uint32_t)lo | ((uint32_t)hi << 16);
            }
            int jg = j0 + jl;
            int sg = ch * 8 + s;
            size_t rowb = ((size_t)n * JPAD + jg) * 128;
            *(uint4*)&yT[rowb + (size_t)((sg ^ (jg & 7)) << 3)] = *(uint4*)dw;
        }
    }
}

__global__ void k_bn1_final(const float* __restrict__ g1, const float* __restrict__ b1, float* ws) {
    int c = threadIdx.x;
    if (c < CC) {
        float s = 0.f, ss = 0.f;
        for (int g = 0; g < 64; ++g) { s += ws[OFF_S1P + c * 64 + g]; ss += ws[OFF_SS1P + c * 64 + g]; }
        const float inv = 1.f / (float)(NN * TV);
        float m = s * inv;
        float var = ss * inv - m * m;
        float rstd = rsqrtf(var + 1e-5f);
        float A = rstd * g1[c];
        ws[OFF_A1 + c] = A;
        ws[OFF_B1 + c] = b1[c] - m * A;
    }
}

// p -> fc1 -> relu -> fc2 -> softmax(logits/tao). one block.
__global__ void k_gate(const float* __restrict__ fc1_w, const float* __restrict__ fc1_b,
                       const float* __restrict__ fc2_w, const float* __restrict__ fc2_b,
                       const float* __restrict__ shift_in,
                       const int* __restrict__ epoch_p, float* ws) {
    __shared__ float psh[NN][CC];
    __shared__ float hsh[NN][RR];
    int tid = threadIdx.x;
    const float invTV = 1.f / (float)TV;
    for (int idx = tid; idx < NN * CC; idx += 256) {
        int n = idx >> 7, c = idx & 127;
        float sh = shift_in[c];
        float gb = (sh >= 0.f) ? (1.f - sh) : (1.f + sh);
        float meang = (299.f + gb) * (1.f / 300.f);
        psh[n][c] = ws[OFF_A1 + c] * (ws[OFF_PS + n * CC + c] * invTV) + ws[OFF_B1 + c] * meang;
    }
    __syncthreads();
    int n = tid >> 2;
    int rq = tid & 3;
    for (int r = rq * 8; r < rq * 8 + 8; ++r) {
        float acc = fc1_b[r];
        for (int c = 0; c < CC; ++c) acc += psh[n][c] * fc1_w[r * CC + c];
        hsh[n][r] = fmaxf(acc, 0.f);
    }
    __syncthreads();
    if (tid < NN) {
        int nn = tid;
        int ep = *epoch_p;
        float tao = (ep < 60) ? (-(29.f / 60.f) * (float)ep + 30.f) : 1.f;
        float li[4];
        float mx = -1e30f;
        for (int k = 0; k < 4; ++k) {
            float acc = fc2_b[k];
            for (int r = 0; r < RR; ++r) acc += hsh[nn][r] * fc2_w[k * RR + r];
            li[k] = acc / tao;
            mx = fmaxf(mx, li[k]);
        }
        float se = 0.f;
        for (int k = 0; k < 4; ++k) { li[k] = expf(li[k] - mx); se += li[k]; }
        float inv = 1.f / se;
        for (int k = 0; k < 4; ++k) ws[OFF_GATE + nn * 4 + k] = li[k] * inv;
    }
}

// wT'[n][d][c] = A_c * (sum_k gate tw) bf16 swizzled, plus bias2/corr terms.
__global__ __launch_bounds__(256) void k_wmix(const float* __restrict__ tw, const float* __restrict__ tb,
                                              const float* __restrict__ shift_in,
                                              float* __restrict__ ws, ushort* __restrict__ wT) {
    int n = blockIdx.x, d = threadIdx.x;
    const float* g = &ws[OFF_GATE + n * 4];
    float g0 = g[0], g1 = g[1], g2 = g[2], g3 = g[3];
    float bias2 = g0 * tb[d] + g1 * tb[DD + d] + g2 * tb[2 * DD + d] + g3 * tb[3 * DD + d];
    float c0acc = 0.f, c9acc = 0.f;
    ushort* wrow = wT + ((size_t)n * DD + d) * 128;
    for (int s = 0; s < 16; ++s) {
        uint32_t dw[4];
#pragma unroll
        for (int h = 0; h < 4; ++h) {
            ushort e01[2];
#pragma unroll
            for (int q = 0; q < 2; ++q) {
                int c = s * 8 + 2 * h + q;
                const float* twc = tw + (size_t)c * DD + d;
                float wv = g0 * twc[0] + g1 * twc[32768] + g2 * twc[65536] + g3 * twc[98304];
                float A = ws[OFF_A1 + c], B = ws[OFF_B1 + c];
                float sh = shift_in[c];
                bias2 += B * wv;
                if (sh >= 0.f) c9acc += B * sh * wv; else c0acc += B * (-sh) * wv;
                e01[q] = f2bf(A * wv);
            }
            dw[h] = (uint32_t)e01[0] | ((uint32_t)e01[1] << 16);
        }
        *(uint4*)&wrow[(s ^ (d & 7)) << 3] = *(uint4*)dw;
    }
    ws[OFF_BIAS2 + n * DD + d] = bias2;
    ws[OFF_CORR0 + n * DD + d] = c0acc;
    ws[OFF_CORR9 + n * DD + d] = c9acc;
}

// MFMA GEMM: per (jt, n) stage y once; dt=0,1 re-stages w half. Epilogue adds B-term.
__global__ __launch_bounds__(256) void k_gemm(const ushort* __restrict__ yT,
                                              const ushort* __restrict__ wT,
                                              const float* __restrict__ ws,
                                              ushort* __restrict__ zbuf) {
    __shared__ ushort yl[128 * 128];
    __shared__ ushort wl[128 * 128];
    int jt = blockIdx.x, n = blockIdx.y;
    int tid = threadIdx.x;
    const char* ysrc = (const char*)(yT + ((size_t)n * JPAD + jt * 128) * 128);
#pragma unroll
    for (int i = 0; i < 8; ++i)
        async_copy16(ysrc + (size_t)(i * 256 + tid) * 16, (char*)yl + (i * 256 + tid) * 16);
    int lane = tid & 63;
    int wid = tid >> 6;
    int wm = wid >> 1, wn = wid & 1;
    int l16 = lane & 15, g = lane >> 4;
    bool edge = (jt == 0) || (jt == 58);
    for (int dt = 0; dt < 2; ++dt) {
        const char* wsrc = (const char*)(wT + ((size_t)n * DD + dt * 128) * 128);
        if (dt) __syncthreads();
#pragma unroll
        for (int i = 0; i < 8; ++i)
            async_copy16(wsrc + (size_t)(i * 256 + tid) * 16, (char*)wl + (i * 256 + tid) * 16);
        __syncthreads();
        f32x4 acc[4][4];
#pragma unroll
        for (int a = 0; a < 4; ++a)
#pragma unroll
            for (int b = 0; b < 4; ++b) acc[a][b] = (f32x4)0.f;
#pragma unroll
        for (int ks = 0; ks < 4; ++ks) {
            short8 af[4], bfr[4];
            int chunk = (ks * 4 + g) ^ (l16 & 7);
#pragma unroll
            for (int mi = 0; mi < 4; ++mi)
                af[mi] = *(const short8*)&wl[(wm * 64 + mi * 16 + l16) * 128 + chunk * 8];
#pragma unroll
            for (int ni = 0; ni < 4; ++ni)
                bfr[ni] = *(const short8*)&yl[(wn * 64 + ni * 16 + l16) * 128 + chunk * 8];
#pragma unroll
            for (int mi = 0; mi < 4; ++mi)
#pragma unroll
                for (int ni = 0; ni < 4; ++ni)
                    acc[mi][ni] = __builtin_amdgcn_mfma_f32_16x16x32_bf16(af[mi], bfr[ni], acc[mi][ni], 0, 0, 0);
        }
#pragma unroll
        for (int mi = 0; mi < 4; ++mi) {
#pragma unroll
            for (int r = 0; r < 4; ++r) {
                int d = dt * 128 + wm * 64 + mi * 16 + g * 4 + r;
                float bias = ws[OFF_BIAS2 + n * DD + d];
                float cr0 = 0.f, cr9 = 0.f;
                if (edge) { cr0 = ws[OFF_CORR0 + n * DD + d]; cr9 = ws[OFF_CORR9 + n * DD + d]; }
                size_t zrow = ((size_t)n * DD + d) * JPAD + jt * 128;
#pragma unroll
                for (int ni = 0; ni < 4; ++ni) {
                    int jl = wn * 64 + ni * 16 + l16;
                    float pre = acc[mi][ni][r] + bias;
                    if (edge) {
                        int jg = jt * 128 + jl;
                        if (jg < VV) pre -= cr0;
                        if (jg >= TV - VV) pre -= cr9;
                    }
                    zbuf[zrow + jl] = f2bf(fmaxf(pre, 0.f));
                }
            }
        }
    }
}

// streaming BN2 stats: stage z row in LDS, 2-tap shifted combine, reduce.
__global__ __launch_bounds__(256) void k_bn2_stats(const ushort* __restrict__ zbuf,
                                                   const float* __restrict__ shift_out,
                                                   float* __restrict__ ws) {
    __shared__ ushort zl[JPAD];
    int d = blockIdx.x & 255;
    int n = blockIdx.x >> 8;
    int tid = threadIdx.x;
    const char* zrow = (const char*)(zbuf + ((size_t)n * DD + d) * JPAD);
    for (int k = tid; k < JPAD / 8; k += 256)
        async_copy16(zrow + (size_t)k * 16, (char*)zl + k * 16);
    __syncthreads();
    float sh = shift_out[d];
    float alpha = (sh >= 0.f) ? (1.f - sh) : (-sh);
    float beta  = (sh >= 0.f) ? sh : (1.f + sh);
    int o25 = (sh >= 0.f) ? 0 : -25;
    float s = 0.f, ss = 0.f;
    for (int jj = tid; jj < TV; jj += 256) {
        int i0 = jj + o25, i1 = jj + o25 + 25;
        float z0 = bf2f(zl[max(i0, 0)]);
        float z1 = bf2f(zl[min(i1, TV - 1)]);
        z0 = (i0 >= 0) ? z0 : 0.f;
        z1 = (i1 < TV) ? z1 : 0.f;
        float zs = alpha * z0 + beta * z1;
        s += zs;
        ss += zs * zs;
    }
    block_reduce2(s, ss);
    if (tid == 0) {
        atomicAdd(&ws[OFF_SUM2 + d], s);
        atomicAdd(&ws[OFF_SUMSQ2 + d], ss);
    }
}

__global__ void k_bn2_final(const float* __restrict__ g2, const float* __restrict__ b2, float* ws) {
    int d = threadIdx.x;
    if (d < DD) {
        const float inv = 1.f / (float)(NN * TV);
        float m = ws[OFF_SUM2 + d] * inv;
        float var = ws[OFF_SUMSQ2 + d] * inv - m * m;
        float rstd = rsqrtf(var + 1e-5f);
        float A = rstd * g2[d];
        ws[OFF_A2 + d] = A;
        ws[OFF_B2 + d] = b2[d] - m * A;
    }
}

// out = shifted(z)*A2 + B2, float4 stores.
__global__ __launch_bounds__(256) void k_out(const ushort* __restrict__ zbuf,
                                             const float* __restrict__ shift_out,
                                             const float* __restrict__ ws,
                                             float* __restrict__ out) {
    __shared__ ushort zl[JPAD];
    int d = blockIdx.x & 255;
    int n = blockIdx.x >> 8;
    int tid = threadIdx.x;
    const char* zrow = (const char*)(zbuf + ((size_t)n * DD + d) * JPAD);
    for (int k = tid; k < JPAD / 8; k += 256)
        async_copy16(zrow + (size_t)k * 16, (char*)zl + k * 16);
    __syncthreads();
    float sh = shift_out[d];
    float alpha = (sh >= 0.f) ? (1.f - sh) : (-sh);
    float beta  = (sh >= 0.f) ? sh : (1.f + sh);
    int o25 = (sh >= 0.f) ? 0 : -25;
    float A = ws[OFF_A2 + d], B = ws[OFF_B2 + d];
    float4* orow = (float4*)(out + ((size_t)n * DD + d) * TV);
    for (int k = tid; k < TV / 4; k += 256) {
        int jj = k * 4;
        float4 o4;
        float* op = &o4.x;
#pragma unroll
        for (int q = 0; q < 4; ++q) {
            int i0 = jj + q + o25, i1 = jj + q + o25 + 25;
            float z0 = bf2f(zl[max(i0, 0)]);
            float z1 = bf2f(zl[min(i1, TV - 1)]);
            z0 = (i0 >= 0) ? z0 : 0.f;
            z1 = (i1 < TV) ? z1 : 0.f;
            op[q] = (alpha * z0 + beta * z1) * A + B;
        }
        orow[k] = o4;
    }
}

extern "C" void kernel_launch(void* const* d_in, const int* in_sizes, int n_in,
                              void* d_out, int out_size, void* d_ws, size_t ws_size,
                              hipStream_t stream) {
    const float* x        = (const float*)d_in[0];
    const int*   epoch    = (const int*)d_in[1];
    const float* bn1_g    = (const float*)d_in[2];
    const float* bn1_b    = (const float*)d_in[3];
    const float* bn2_g    = (const float*)d_in[4];
    const float* bn2_b    = (const float*)d_in[5];
    const float* shift_in = (const float*)d_in[6];
    const float* shift_out= (const float*)d_in[7];
    const float* fc1_w    = (const float*)d_in[8];
    const float* fc1_b    = (const float*)d_in[9];
    const float* fc2_w    = (const float*)d_in[10];
    const float* fc2_b    = (const float*)d_in[11];
    const float* tw       = (const float*)d_in[12];
    const float* tb       = (const float*)d_in[13];
    float* out = (float*)d_out;
    float* ws  = (float*)d_ws;
    ushort* yT = (ushort*)d_out;                    // parked in d_out until k_out
    ushort* wT = (ushort*)((char*)d_ws + WT_BYTE_OFF);
    ushort* zb = (ushort*)((char*)d_ws + Z_BYTE_OFF);

    k_zero<<<32, 256, 0, stream>>>(ws);
    k_shift_stats<<<dim3(NJT, 2, NN), 256, 0, stream>>>(x, shift_in, ws, yT);
    k_bn1_final<<<1, 128, 0, stream>>>(bn1_g, bn1_b, ws);
    k_gate<<<1, 256, 0, stream>>>(fc1_w, fc1_b, fc2_w, fc2_b, shift_in, epoch, ws);
    k_wmix<<<64, 256, 0, stream>>>(tw, tb, shift_in, ws, wT);
    k_gemm<<<dim3(59, 64), 256, 0, stream>>>(yT, wT, ws, zb);
    k_bn2_stats<<<16384, 256, 0, stream>>>(zb, shift_out, ws);
    k_bn2_final<<<1, 256, 0, stream>>>(bn2_g, bn2_b, ws);
    k_out<<<16384, 256, 0, stream>>>(zb, shift_out, ws, out);
}

// Round 6
// 507.763 us; speedup vs baseline: 1.3242x; 1.1795x over previous
//
#include <hip/hip_runtime.h>
#include <stdint.h>

#define NN 64
#define CC 128
#define TT 300
#define VV 25
#define TV 7500
#define DD 256
#define RR 32
#define JPAD 7552   // padded row stride for yT and z (59*128)
#define JT 125      // shift kernel j-tile (exactly 5 t-columns)
#define NJT 60
#define XSTR4 184   // xw float stride per c-row (46 float4, 16B aligned)
#define XROWB (XSTR4 * 4)
#define CBL 32      // c per shift block

// ws float offsets
#define OFF_S1P    0          // [c][64] partial x sums
#define OFF_SS1P   8192       // [c][64] partial x sumsq
#define OFF_PS     16384      // [n][c] xs sums
#define OFF_A1     24576
#define OFF_B1     24704
#define OFF_SUM2   24832
#define OFF_SUMSQ2 25088
#define OFF_A2     25344
#define OFF_B2     25600
#define OFF_GATE   25856
#define OFF_BIAS2  26112      // [n][d]
#define OFF_CORR0  42496      // [n][d]
#define OFF_CORR9  58880      // [n][d]
#define FLOAT_REGION 75264
#define ZERO_CNT   25344
#define WT_BYTE_OFF ((size_t)FLOAT_REGION * 4)
#define WT_BYTES    ((size_t)NN * DD * CC * 2)
#define Z_BYTE_OFF  (WT_BYTE_OFF + WT_BYTES)

typedef __attribute__((ext_vector_type(8))) short short8;
typedef __attribute__((ext_vector_type(4))) float f32x4;

typedef const __attribute__((address_space(1))) uint32_t gas_u32;
typedef __attribute__((address_space(3))) uint32_t las_u32;

__device__ inline ushort f2bf(float f) {
    uint32_t u = __float_as_uint(f);
    u += 0x7fffu + ((u >> 16) & 1u);
    return (ushort)(u >> 16);
}
__device__ inline float bf2f(ushort v) { return __uint_as_float(((uint32_t)v) << 16); }
__device__ inline void async_copy16(const void* g, void* l) {
    __builtin_amdgcn_global_load_lds((gas_u32*)g, (las_u32*)l, 16, 0, 0);
}

__device__ inline void block_reduce2(float& a, float& b) {
    __shared__ float sa[4], sb[4];
    for (int off = 32; off > 0; off >>= 1) {
        a += __shfl_down(a, off);
        b += __shfl_down(b, off);
    }
    int lane = threadIdx.x & 63, wid = threadIdx.x >> 6;
    if (lane == 0) { sa[wid] = a; sb[wid] = b; }
    __syncthreads();
    if (threadIdx.x == 0) {
        a = sa[0] + sa[1] + sa[2] + sa[3];
        b = sb[0] + sb[1] + sb[2] + sb[3];
    }
}

__global__ void k_zero(float* ws) {
    int i = blockIdx.x * 256 + threadIdx.x;
    for (; i < ZERO_CNT; i += 32 * 256) ws[i] = 0.f;
}

// Streaming shift+stats v2: x window staged via global_load_lds (no VGPR trip),
// 32 c/block, 31.7 KB LDS -> 5 blocks/CU. grid (60 jt, 4 c-grp, 64 n).
__global__ __launch_bounds__(256) void k_shift_stats(const float* __restrict__ x,
                                                     const float* __restrict__ shift_in,
                                                     float* __restrict__ ws,
                                                     ushort* __restrict__ yT) {
    __shared__ float  xw[CBL * XSTR4];    // 23552 B
    __shared__ ushort ytile[CBL * 128];   // 8192 B
    int jt = blockIdx.x, ch = blockIdx.y, n = blockIdx.z;
    int j0 = jt * JT;
    int t0 = jt * 5;
    int t_lo = max(t0 - 1, 0);
    int start_f = (t_lo * VV) & ~3;
    int doff = t_lo * VV - start_f;
    int tid = threadIdx.x;
    int lane = tid & 63, w = tid >> 6;
    int nvalid = min(45, (TV - start_f) >> 2);   // full-16B lanes in row (38 at jt=59)

    // ---- stage: wave w copies c-rows w*8..w*8+7, 45(38) lanes x 16B each ----
    const float* xbase = x + ((size_t)n * CC + ch * CBL) * TV;
#pragma unroll
    for (int rr = 0; rr < 8; ++rr) {
        int cl = w * 8 + rr;
        if (lane < nvalid)
            async_copy16((const char*)(xbase + (size_t)cl * TV + start_f) + lane * 16,
                         (char*)xw + cl * XROWB + lane * 16);
    }
    __syncthreads();

    // ---- gather from LDS + stats + pack into ytile ----
    int jq = tid & 7;       // j-chunk of 8
    int cl = tid >> 3;      // local c 0..31
    {
        int c = ch * CBL + cl;
        float sh = shift_in[c];
        bool posi = (sh >= 0.f);
        const float* xrow = &xw[cl * XSTR4];
        float s_p = 0.f, s_x = 0.f, s_xx = 0.f;
        int key = (cl & 7) ^ ((cl >> 3) & 7);
        for (int p = 0; p < 2; ++p) {
            int jb = p * 64 + jq * 8;
            ushort pk[8];
#pragma unroll
            for (int e = 0; e < 8; ++e) {
                int jtl = jb + e;
                float yv = 0.f, xv = 0.f;
                if (jtl < JT) {
                    int j = j0 + jtl;
                    int t = j / VV;
                    int v = j - t * VV;
                    float posf = (float)t + sh;
                    float f0 = floorf(posf);
                    int i0 = (int)f0;
                    float frac = posf - f0;
                    int i1 = i0 + 1;
                    float w0 = (i0 >= 0 && i0 < TT) ? (1.f - frac) : 0.f;
                    float w1 = (i1 >= 0 && i1 < TT) ? frac : 0.f;
                    int i0c = min(max(i0, 0), TT - 1), i1c = min(max(i1, 0), TT - 1);
                    float x0 = xrow[(i0c - t_lo) * VV + v + doff];
                    float x1 = xrow[(i1c - t_lo) * VV + v + doff];
                    yv = w0 * x0 + w1 * x1;
                    xv = posi ? x0 : x1;     // == x[j] exactly
                }
                s_p += yv; s_x += xv; s_xx += xv * xv;
                pk[e] = f2bf(yv);
            }
            uint32_t dw[4];
#pragma unroll
            for (int h = 0; h < 4; ++h) dw[h] = (uint32_t)pk[2 * h] | ((uint32_t)pk[2 * h + 1] << 16);
            int m = p * 8 + (jq ^ key);
            *(uint4*)&ytile[cl * 128 + m * 8] = *(uint4*)dw;
        }
        for (int off = 4; off > 0; off >>= 1) {
            s_p += __shfl_down(s_p, off, 8);
            s_x += __shfl_down(s_x, off, 8);
            s_xx += __shfl_down(s_xx, off, 8);
        }
        if (jq == 0) {
            atomicAdd(&ws[OFF_PS + n * CC + c], s_p);
            atomicAdd(&ws[OFF_S1P + c * 64 + n], s_x);
            atomicAdd(&ws[OFF_SS1P + c * 64 + n], s_xx);
        }
    }
    __syncthreads();

    // ---- transpose read + coalesced swizzled store: 125 jl x 4 s-chunks ----
    for (int it = 0; it < 2; ++it) {
        int idx = it * 256 + tid;
        int s = idx & 3;          // local c-chunk
        int jl = idx >> 2;        // 0..127
        if (jl < JT) {
            int p = jl >> 6, jqv = (jl >> 3) & 7, e = jl & 7;
            uint32_t dw[4];
#pragma unroll
            for (int h = 0; h < 4; ++h) {
                int c0 = 8 * s + 2 * h, c1 = c0 + 1;
                int m0 = p * 8 + (jqv ^ (c0 & 7) ^ s);
                int m1 = p * 8 + (jqv ^ (c1 & 7) ^ s);
                ushort lo = ytile[c0 * 128 + m0 * 8 + e];
                ushort hi = ytile[c1 * 128 + m1 * 8 + e];
                dw[h] = (uint32_t)lo | ((uint32_t)hi << 16);
            }
            int jg = j0 + jl;
            int sg = ch * 4 + s;
            size_t rowb = ((size_t)n * JPAD + jg) * 128;
            *(uint4*)&yT[rowb + (size_t)((sg ^ (jg & 7)) << 3)] = *(uint4*)dw;
        }
    }
}

__global__ void k_bn1_final(const float* __restrict__ g1, const float* __restrict__ b1, float* ws) {
    int c = threadIdx.x;
    if (c < CC) {
        float s = 0.f, ss = 0.f;
        for (int g = 0; g < 64; ++g) { s += ws[OFF_S1P + c * 64 + g]; ss += ws[OFF_SS1P + c * 64 + g]; }
        const float inv = 1.f / (float)(NN * TV);
        float m = s * inv;
        float var = ss * inv - m * m;
        float rstd = rsqrtf(var + 1e-5f);
        float A = rstd * g1[c];
        ws[OFF_A1 + c] = A;
        ws[OFF_B1 + c] = b1[c] - m * A;
    }
}

// p -> fc1 -> relu -> fc2 -> softmax(logits/tao). one block.
__global__ void k_gate(const float* __restrict__ fc1_w, const float* __restrict__ fc1_b,
                       const float* __restrict__ fc2_w, const float* __restrict__ fc2_b,
                       const float* __restrict__ shift_in,
                       const int* __restrict__ epoch_p, float* ws) {
    __shared__ float psh[NN][CC];
    __shared__ float hsh[NN][RR];
    int tid = threadIdx.x;
    const float invTV = 1.f / (float)TV;
    for (int idx = tid; idx < NN * CC; idx += 256) {
        int n = idx >> 7, c = idx & 127;
        float sh = shift_in[c];
        float gb = (sh >= 0.f) ? (1.f - sh) : (1.f + sh);
        float meang = (299.f + gb) * (1.f / 300.f);
        psh[n][c] = ws[OFF_A1 + c] * (ws[OFF_PS + n * CC + c] * invTV) + ws[OFF_B1 + c] * meang;
    }
    __syncthreads();
    int n = tid >> 2;
    int rq = tid & 3;
    for (int r = rq * 8; r < rq * 8 + 8; ++r) {
        float acc = fc1_b[r];
        for (int c = 0; c < CC; ++c) acc += psh[n][c] * fc1_w[r * CC + c];
        hsh[n][r] = fmaxf(acc, 0.f);
    }
    __syncthreads();
    if (tid < NN) {
        int nn = tid;
        int ep = *epoch_p;
        float tao = (ep < 60) ? (-(29.f / 60.f) * (float)ep + 30.f) : 1.f;
        float li[4];
        float mx = -1e30f;
        for (int k = 0; k < 4; ++k) {
            float acc = fc2_b[k];
            for (int r = 0; r < RR; ++r) acc += hsh[nn][r] * fc2_w[k * RR + r];
            li[k] = acc / tao;
            mx = fmaxf(mx, li[k]);
        }
        float se = 0.f;
        for (int k = 0; k < 4; ++k) { li[k] = expf(li[k] - mx); se += li[k]; }
        float inv = 1.f / se;
        for (int k = 0; k < 4; ++k) ws[OFF_GATE + nn * 4 + k] = li[k] * inv;
    }
}

// wT'[n][d][c] = A_c * (sum_k gate tw) bf16 swizzled, plus bias2/corr terms.
__global__ __launch_bounds__(256) void k_wmix(const float* __restrict__ tw, const float* __restrict__ tb,
                                              const float* __restrict__ shift_in,
                                              float* __restrict__ ws, ushort* __restrict__ wT) {
    int n = blockIdx.x, d = threadIdx.x;
    const float* g = &ws[OFF_GATE + n * 4];
    float g0 = g[0], g1 = g[1], g2 = g[2], g3 = g[3];
    float bias2 = g0 * tb[d] + g1 * tb[DD + d] + g2 * tb[2 * DD + d] + g3 * tb[3 * DD + d];
    float c0acc = 0.f, c9acc = 0.f;
    ushort* wrow = wT + ((size_t)n * DD + d) * 128;
    for (int s = 0; s < 16; ++s) {
        uint32_t dw[4];
#pragma unroll
        for (int h = 0; h < 4; ++h) {
            ushort e01[2];
#pragma unroll
            for (int q = 0; q < 2; ++q) {
                int c = s * 8 + 2 * h + q;
                const float* twc = tw + (size_t)c * DD + d;
                float wv = g0 * twc[0] + g1 * twc[32768] + g2 * twc[65536] + g3 * twc[98304];
                float A = ws[OFF_A1 + c], B = ws[OFF_B1 + c];
                float sh = shift_in[c];
                bias2 += B * wv;
                if (sh >= 0.f) c9acc += B * sh * wv; else c0acc += B * (-sh) * wv;
                e01[q] = f2bf(A * wv);
            }
            dw[h] = (uint32_t)e01[0] | ((uint32_t)e01[1] << 16);
        }
        *(uint4*)&wrow[(s ^ (d & 7)) << 3] = *(uint4*)dw;
    }
    ws[OFF_BIAS2 + n * DD + d] = bias2;
    ws[OFF_CORR0 + n * DD + d] = c0acc;
    ws[OFF_CORR9 + n * DD + d] = c9acc;
}

// MFMA GEMM v2: y staged once; w in 4 chunks of 64d, double-buffered,
// next chunk issued before compute (2-phase pipeline, plain barriers).
__global__ __launch_bounds__(256) void k_gemm(const ushort* __restrict__ yT,
                                              const ushort* __restrict__ wT,
                                              const float* __restrict__ ws,
                                              ushort* __restrict__ zbuf) {
    __shared__ ushort yl[128 * 128];      // 32 KB
    __shared__ ushort wl[2][64 * 128];    // 2 x 16 KB
    int jt = blockIdx.x, n = blockIdx.y;
    int tid = threadIdx.x;
    const char* ysrc = (const char*)(yT + ((size_t)n * JPAD + jt * 128) * 128);
    const char* wsrc = (const char*)(wT + (size_t)n * DD * 128);
#pragma unroll
    for (int i = 0; i < 8; ++i)
        async_copy16(ysrc + (size_t)(i * 256 + tid) * 16, (char*)yl + (i * 256 + tid) * 16);
#pragma unroll
    for (int i = 0; i < 4; ++i)
        async_copy16(wsrc + (size_t)(i * 256 + tid) * 16, (char*)wl[0] + (i * 256 + tid) * 16);
    __syncthreads();
    int lane = tid & 63, wid = tid >> 6;
    int wm = wid >> 1, wn = wid & 1;
    int l16 = lane & 15, g = lane >> 4;
    bool edge = (jt == 0) || (jt == 58);
#pragma unroll
    for (int dt = 0; dt < 4; ++dt) {
        if (dt < 3) {      // prefetch next 64d chunk into the other buffer
            const char* wc = wsrc + (size_t)(dt + 1) * 16384;
#pragma unroll
            for (int i = 0; i < 4; ++i)
                async_copy16(wc + (size_t)(i * 256 + tid) * 16,
                             (char*)wl[(dt + 1) & 1] + (i * 256 + tid) * 16);
        }
        const ushort* wcur = wl[dt & 1];
        f32x4 acc[2][4];
#pragma unroll
        for (int a = 0; a < 2; ++a)
#pragma unroll
            for (int b = 0; b < 4; ++b) acc[a][b] = (f32x4)0.f;
#pragma unroll
        for (int ks = 0; ks < 4; ++ks) {
            short8 af[2], bfr[4];
            int chunk = (ks * 4 + g) ^ (l16 & 7);
#pragma unroll
            for (int mi = 0; mi < 2; ++mi)
                af[mi] = *(const short8*)&wcur[(wm * 32 + mi * 16 + l16) * 128 + chunk * 8];
#pragma unroll
            for (int ni = 0; ni < 4; ++ni)
                bfr[ni] = *(const short8*)&yl[(wn * 64 + ni * 16 + l16) * 128 + chunk * 8];
#pragma unroll
            for (int mi = 0; mi < 2; ++mi)
#pragma unroll
                for (int ni = 0; ni < 4; ++ni)
                    acc[mi][ni] = __builtin_amdgcn_mfma_f32_16x16x32_bf16(af[mi], bfr[ni], acc[mi][ni], 0, 0, 0);
        }
#pragma unroll
        for (int mi = 0; mi < 2; ++mi) {
#pragma unroll
            for (int r = 0; r < 4; ++r) {
                int d = dt * 64 + wm * 32 + mi * 16 + g * 4 + r;
                float bias = ws[OFF_BIAS2 + n * DD + d];
                float cr0 = 0.f, cr9 = 0.f;
                if (edge) { cr0 = ws[OFF_CORR0 + n * DD + d]; cr9 = ws[OFF_CORR9 + n * DD + d]; }
                size_t zrow = ((size_t)n * DD + d) * JPAD + jt * 128;
#pragma unroll
                for (int ni = 0; ni < 4; ++ni) {
                    int jl = wn * 64 + ni * 16 + l16;
                    float pre = acc[mi][ni][r] + bias;
                    if (edge) {
                        int jg = jt * 128 + jl;
                        if (jg < VV) pre -= cr0;
                        if (jg >= TV - VV) pre -= cr9;
                    }
                    zbuf[zrow + jl] = f2bf(fmaxf(pre, 0.f));
                }
            }
        }
        __syncthreads();   // drains prefetch; frees wl[dt&1] for dt+2
    }
}

// streaming BN2 stats: stage z row in LDS, 2-tap shifted combine, reduce.
__global__ __launch_bounds__(256) void k_bn2_stats(const ushort* __restrict__ zbuf,
                                                   const float* __restrict__ shift_out,
                                                   float* __restrict__ ws) {
    __shared__ ushort zl[JPAD];
    int d = blockIdx.x & 255;
    int n = blockIdx.x >> 8;
    int tid = threadIdx.x;
    const char* zrow = (const char*)(zbuf + ((size_t)n * DD + d) * JPAD);
    for (int k = tid; k < JPAD / 8; k += 256)
        async_copy16(zrow + (size_t)k * 16, (char*)zl + k * 16);
    __syncthreads();
    float sh = shift_out[d];
    float alpha = (sh >= 0.f) ? (1.f - sh) : (-sh);
    float beta  = (sh >= 0.f) ? sh : (1.f + sh);
    int o25 = (sh >= 0.f) ? 0 : -25;
    float s = 0.f, ss = 0.f;
    for (int jj = tid; jj < TV; jj += 256) {
        int i0 = jj + o25, i1 = jj + o25 + 25;
        float z0 = bf2f(zl[max(i0, 0)]);
        float z1 = bf2f(zl[min(i1, TV - 1)]);
        z0 = (i0 >= 0) ? z0 : 0.f;
        z1 = (i1 < TV) ? z1 : 0.f;
        float zs = alpha * z0 + beta * z1;
        s += zs;
        ss += zs * zs;
    }
    block_reduce2(s, ss);
    if (tid == 0) {
        atomicAdd(&ws[OFF_SUM2 + d], s);
        atomicAdd(&ws[OFF_SUMSQ2 + d], ss);
    }
}

__global__ void k_bn2_final(const float* __restrict__ g2, const float* __restrict__ b2, float* ws) {
    int d = threadIdx.x;
    if (d < DD) {
        const float inv = 1.f / (float)(NN * TV);
        float m = ws[OFF_SUM2 + d] * inv;
        float var = ws[OFF_SUMSQ2 + d] * inv - m * m;
        float rstd = rsqrtf(var + 1e-5f);
        float A = rstd * g2[d];
        ws[OFF_A2 + d] = A;
        ws[OFF_B2 + d] = b2[d] - m * A;
    }
}

// out = shifted(z)*A2 + B2, float4 stores.
__global__ __launch_bounds__(256) void k_out(const ushort* __restrict__ zbuf,
                                             const float* __restrict__ shift_out,
                                             const float* __restrict__ ws,
                                             float* __restrict__ out) {
    __shared__ ushort zl[JPAD];
    int d = blockIdx.x & 255;
    int n = blockIdx.x >> 8;
    int tid = threadIdx.x;
    const char* zrow = (const char*)(zbuf + ((size_t)n * DD + d) * JPAD);
    for (int k = tid; k < JPAD / 8; k += 256)
        async_copy16(zrow + (size_t)k * 16, (char*)zl + k * 16);
    __syncthreads();
    float sh = shift_out[d];
    float alpha = (sh >= 0.f) ? (1.f - sh) : (-sh);
    float beta  = (sh >= 0.f) ? sh : (1.f + sh);
    int o25 = (sh >= 0.f) ? 0 : -25;
    float A = ws[OFF_A2 + d], B = ws[OFF_B2 + d];
    float4* orow = (float4*)(out + ((size_t)n * DD + d) * TV);
    for (int k = tid; k < TV / 4; k += 256) {
        int jj = k * 4;
        float4 o4;
        float* op = &o4.x;
#pragma unroll
        for (int q = 0; q < 4; ++q) {
            int i0 = jj + q + o25, i1 = jj + q + o25 + 25;
            float z0 = bf2f(zl[max(i0, 0)]);
            float z1 = bf2f(zl[min(i1, TV - 1)]);
            z0 = (i0 >= 0) ? z0 : 0.f;
            z1 = (i1 < TV) ? z1 : 0.f;
            op[q] = (alpha * z0 + beta * z1) * A + B;
        }
        orow[k] = o4;
    }
}

extern "C" void kernel_launch(void* const* d_in, const int* in_sizes, int n_in,
                              void* d_out, int out_size, void* d_ws, size_t ws_size,
                              hipStream_t stream) {
    const float* x        = (const float*)d_in[0];
    const int*   epoch    = (const int*)d_in[1];
    const float* bn1_g    = (const float*)d_in[2];
    const float* bn1_b    = (const float*)d_in[3];
    const float* bn2_g    = (const float*)d_in[4];
    const float* bn2_b    = (const float*)d_in[5];
    const float* shift_in = (const float*)d_in[6];
    const float* shift_out= (const float*)d_in[7];
    const float* fc1_w    = (const float*)d_in[8];
    const float* fc1_b    = (const float*)d_in[9];
    const float* fc2_w    = (const float*)d_in[10];
    const float* fc2_b    = (const float*)d_in[11];
    const float* tw       = (const float*)d_in[12];
    const float* tb       = (const float*)d_in[13];
    float* out = (float*)d_out;
    float* ws  = (float*)d_ws;
    ushort* yT = (ushort*)d_out;                    // parked in d_out until k_out
    ushort* wT = (ushort*)((char*)d_ws + WT_BYTE_OFF);
    ushort* zb = (ushort*)((char*)d_ws + Z_BYTE_OFF);

    k_zero<<<32, 256, 0, stream>>>(ws);
    k_shift_stats<<<dim3(NJT, 4, NN), 256, 0, stream>>>(x, shift_in, ws, yT);
    k_bn1_final<<<1, 128, 0, stream>>>(bn1_g, bn1_b, ws);
    k_gate<<<1, 256, 0, stream>>>(fc1_w, fc1_b, fc2_w, fc2_b, shift_in, epoch, ws);
    k_wmix<<<64, 256, 0, stream>>>(tw, tb, shift_in, ws, wT);
    k_gemm<<<dim3(59, 64), 256, 0, stream>>>(yT, wT, ws, zb);
    k_bn2_stats<<<16384, 256, 0, stream>>>(zb, shift_out, ws);
    k_bn2_final<<<1, 256, 0, stream>>>(bn2_g, bn2_b, ws);
    k_out<<<16384, 256, 0, stream>>>(zb, shift_out, ws, out);
}

// Round 7
// 486.984 us; speedup vs baseline: 1.3807x; 1.0427x over previous
//
#include <hip/hip_runtime.h>
#include <stdint.h>

#define NN 64
#define CC 128
#define TT 300
#define VV 25
#define TV 7500
#define DD 256
#define RR 32
#define JPAD 7552   // padded row stride for yT and z (59*128)
#define JT 125      // shift kernel j-tile (exactly 5 t-columns)
#define NJT 60
#define XSTR4 184   // xw float stride per c-row (46 float4, 16B aligned)
#define XROWB (XSTR4 * 4)
#define CBL 32      // c per shift block
#define ZSTR 136    // zst ushort stride (272B = 17 x 16B)

// ws float offsets
#define OFF_S1P    0          // [c][64] partial x sums
#define OFF_SS1P   8192       // [c][64] partial x sumsq
#define OFF_PS     16384      // [n][c] xs sums
#define OFF_A1     24576
#define OFF_B1     24704
#define OFF_SUM2   24832
#define OFF_SUMSQ2 25088
#define OFF_GATE   25856
#define OFF_BIAS2  26112      // [n][d]
#define OFF_CORR0  42496      // [n][d]
#define OFF_CORR9  58880      // [n][d]
#define FLOAT_REGION 75264
#define ZERO_CNT   25344
#define WT_BYTE_OFF ((size_t)FLOAT_REGION * 4)
#define WT_BYTES    ((size_t)NN * DD * CC * 2)
#define Z_BYTE_OFF  (WT_BYTE_OFF + WT_BYTES)

typedef __attribute__((ext_vector_type(8))) short short8;
typedef __attribute__((ext_vector_type(4))) float f32x4;

typedef const __attribute__((address_space(1))) uint32_t gas_u32;
typedef __attribute__((address_space(3))) uint32_t las_u32;

__device__ inline ushort f2bf(float f) {
    uint32_t u = __float_as_uint(f);
    u += 0x7fffu + ((u >> 16) & 1u);
    return (ushort)(u >> 16);
}
__device__ inline float bf2f(ushort v) { return __uint_as_float(((uint32_t)v) << 16); }
__device__ inline void async_copy16(const void* g, void* l) {
    __builtin_amdgcn_global_load_lds((gas_u32*)g, (las_u32*)l, 16, 0, 0);
}

__device__ inline void block_reduce2(float& a, float& b) {
    __shared__ float sa[4], sb[4];
    for (int off = 32; off > 0; off >>= 1) {
        a += __shfl_down(a, off);
        b += __shfl_down(b, off);
    }
    int lane = threadIdx.x & 63, wid = threadIdx.x >> 6;
    if (lane == 0) { sa[wid] = a; sb[wid] = b; }
    __syncthreads();
    if (threadIdx.x == 0) {
        a = sa[0] + sa[1] + sa[2] + sa[3];
        b = sb[0] + sb[1] + sb[2] + sb[3];
    }
}

__global__ void k_zero(float* ws) {
    int i = blockIdx.x * 256 + threadIdx.x;
    for (; i < ZERO_CNT; i += 32 * 256) ws[i] = 0.f;
}

// Streaming shift+stats: x window staged via global_load_lds, 32 c/block.
__global__ __launch_bounds__(256) void k_shift_stats(const float* __restrict__ x,
                                                     const float* __restrict__ shift_in,
                                                     float* __restrict__ ws,
                                                     ushort* __restrict__ yT) {
    __shared__ float  xw[CBL * XSTR4];    // 23552 B
    __shared__ ushort ytile[CBL * 128];   // 8192 B
    int jt = blockIdx.x, ch = blockIdx.y, n = blockIdx.z;
    int j0 = jt * JT;
    int t0 = jt * 5;
    int t_lo = max(t0 - 1, 0);
    int start_f = (t_lo * VV) & ~3;
    int doff = t_lo * VV - start_f;
    int tid = threadIdx.x;
    int lane = tid & 63, w = tid >> 6;
    int nvalid = min(45, (TV - start_f) >> 2);

    const float* xbase = x + ((size_t)n * CC + ch * CBL) * TV;
#pragma unroll
    for (int rr = 0; rr < 8; ++rr) {
        int cl = w * 8 + rr;
        if (lane < nvalid)
            async_copy16((const char*)(xbase + (size_t)cl * TV + start_f) + lane * 16,
                         (char*)xw + cl * XROWB + lane * 16);
    }
    __syncthreads();

    int jq = tid & 7;
    int cl = tid >> 3;
    {
        int c = ch * CBL + cl;
        float sh = shift_in[c];
        bool posi = (sh >= 0.f);
        const float* xrow = &xw[cl * XSTR4];
        float s_p = 0.f, s_x = 0.f, s_xx = 0.f;
        int key = (cl & 7) ^ ((cl >> 3) & 7);
        for (int p = 0; p < 2; ++p) {
            int jb = p * 64 + jq * 8;
            ushort pk[8];
#pragma unroll
            for (int e = 0; e < 8; ++e) {
                int jtl = jb + e;
                float yv = 0.f, xv = 0.f;
                if (jtl < JT) {
                    int j = j0 + jtl;
                    int t = j / VV;
                    int v = j - t * VV;
                    float posf = (float)t + sh;
                    float f0 = floorf(posf);
                    int i0 = (int)f0;
                    float frac = posf - f0;
                    int i1 = i0 + 1;
                    float w0 = (i0 >= 0 && i0 < TT) ? (1.f - frac) : 0.f;
                    float w1 = (i1 >= 0 && i1 < TT) ? frac : 0.f;
                    int i0c = min(max(i0, 0), TT - 1), i1c = min(max(i1, 0), TT - 1);
                    float x0 = xrow[(i0c - t_lo) * VV + v + doff];
                    float x1 = xrow[(i1c - t_lo) * VV + v + doff];
                    yv = w0 * x0 + w1 * x1;
                    xv = posi ? x0 : x1;     // == x[j] exactly
                }
                s_p += yv; s_x += xv; s_xx += xv * xv;
                pk[e] = f2bf(yv);
            }
            uint32_t dw[4];
#pragma unroll
            for (int h = 0; h < 4; ++h) dw[h] = (uint32_t)pk[2 * h] | ((uint32_t)pk[2 * h + 1] << 16);
            int m = p * 8 + (jq ^ key);
            *(uint4*)&ytile[cl * 128 + m * 8] = *(uint4*)dw;
        }
        for (int off = 4; off > 0; off >>= 1) {
            s_p += __shfl_down(s_p, off, 8);
            s_x += __shfl_down(s_x, off, 8);
            s_xx += __shfl_down(s_xx, off, 8);
        }
        if (jq == 0) {
            atomicAdd(&ws[OFF_PS + n * CC + c], s_p);
            atomicAdd(&ws[OFF_S1P + c * 64 + n], s_x);
            atomicAdd(&ws[OFF_SS1P + c * 64 + n], s_xx);
        }
    }
    __syncthreads();

    for (int it = 0; it < 2; ++it) {
        int idx = it * 256 + tid;
        int s = idx & 3;
        int jl = idx >> 2;
        if (jl < JT) {
            int p = jl >> 6, jqv = (jl >> 3) & 7, e = jl & 7;
            uint32_t dw[4];
#pragma unroll
            for (int h = 0; h < 4; ++h) {
                int c0 = 8 * s + 2 * h, c1 = c0 + 1;
                int m0 = p * 8 + (jqv ^ (c0 & 7) ^ s);
                int m1 = p * 8 + (jqv ^ (c1 & 7) ^ s);
                ushort lo = ytile[c0 * 128 + m0 * 8 + e];
                ushort hi = ytile[c1 * 128 + m1 * 8 + e];
                dw[h] = (uint32_t)lo | ((uint32_t)hi << 16);
            }
            int jg = j0 + jl;
            int sg = ch * 4 + s;
            size_t rowb = ((size_t)n * JPAD + jg) * 128;
            *(uint4*)&yT[rowb + (size_t)((sg ^ (jg & 7)) << 3)] = *(uint4*)dw;
        }
    }
}

// bn1_final + p -> fc1 -> relu -> fc2 -> softmax. one block.
__global__ void k_gate(const float* __restrict__ g1, const float* __restrict__ b1,
                       const float* __restrict__ fc1_w, const float* __restrict__ fc1_b,
                       const float* __restrict__ fc2_w, const float* __restrict__ fc2_b,
                       const float* __restrict__ shift_in,
                       const int* __restrict__ epoch_p, float* ws) {
    __shared__ float psh[NN][CC];
    __shared__ float hsh[NN][RR];
    int tid = threadIdx.x;
    if (tid < CC) {
        int c = tid;
        float s = 0.f, ss = 0.f;
        for (int g = 0; g < 64; ++g) { s += ws[OFF_S1P + c * 64 + g]; ss += ws[OFF_SS1P + c * 64 + g]; }
        const float inv = 1.f / (float)(NN * TV);
        float m = s * inv;
        float var = ss * inv - m * m;
        float rstd = rsqrtf(var + 1e-5f);
        float A = rstd * g1[c];
        ws[OFF_A1 + c] = A;
        ws[OFF_B1 + c] = b1[c] - m * A;
    }
    __syncthreads();
    const float invTV = 1.f / (float)TV;
    for (int idx = tid; idx < NN * CC; idx += 256) {
        int n = idx >> 7, c = idx & 127;
        float sh = shift_in[c];
        float gb = (sh >= 0.f) ? (1.f - sh) : (1.f + sh);
        float meang = (299.f + gb) * (1.f / 300.f);
        psh[n][c] = ws[OFF_A1 + c] * (ws[OFF_PS + n * CC + c] * invTV) + ws[OFF_B1 + c] * meang;
    }
    __syncthreads();
    int n = tid >> 2;
    int rq = tid & 3;
    for (int r = rq * 8; r < rq * 8 + 8; ++r) {
        float acc = fc1_b[r];
        for (int c = 0; c < CC; ++c) acc += psh[n][c] * fc1_w[r * CC + c];
        hsh[n][r] = fmaxf(acc, 0.f);
    }
    __syncthreads();
    if (tid < NN) {
        int nn = tid;
        int ep = *epoch_p;
        float tao = (ep < 60) ? (-(29.f / 60.f) * (float)ep + 30.f) : 1.f;
        float li[4];
        float mx = -1e30f;
        for (int k = 0; k < 4; ++k) {
            float acc = fc2_b[k];
            for (int r = 0; r < RR; ++r) acc += hsh[nn][r] * fc2_w[k * RR + r];
            li[k] = acc / tao;
            mx = fmaxf(mx, li[k]);
        }
        float se = 0.f;
        for (int k = 0; k < 4; ++k) { li[k] = expf(li[k] - mx); se += li[k]; }
        float inv = 1.f / se;
        for (int k = 0; k < 4; ++k) ws[OFF_GATE + nn * 4 + k] = li[k] * inv;
    }
}

// wT'[n][d][c] = A_c * (sum_k gate tw) bf16 swizzled, plus bias2/corr terms.
__global__ __launch_bounds__(256) void k_wmix(const float* __restrict__ tw, const float* __restrict__ tb,
                                              const float* __restrict__ shift_in,
                                              float* __restrict__ ws, ushort* __restrict__ wT) {
    int n = blockIdx.x, d = threadIdx.x;
    const float* g = &ws[OFF_GATE + n * 4];
    float g0 = g[0], g1 = g[1], g2 = g[2], g3 = g[3];
    float bias2 = g0 * tb[d] + g1 * tb[DD + d] + g2 * tb[2 * DD + d] + g3 * tb[3 * DD + d];
    float c0acc = 0.f, c9acc = 0.f;
    ushort* wrow = wT + ((size_t)n * DD + d) * 128;
    for (int s = 0; s < 16; ++s) {
        uint32_t dw[4];
#pragma unroll
        for (int h = 0; h < 4; ++h) {
            ushort e01[2];
#pragma unroll
            for (int q = 0; q < 2; ++q) {
                int c = s * 8 + 2 * h + q;
                const float* twc = tw + (size_t)c * DD + d;
                float wv = g0 * twc[0] + g1 * twc[32768] + g2 * twc[65536] + g3 * twc[98304];
                float A = ws[OFF_A1 + c], B = ws[OFF_B1 + c];
                float sh = shift_in[c];
                bias2 += B * wv;
                if (sh >= 0.f) c9acc += B * sh * wv; else c0acc += B * (-sh) * wv;
                e01[q] = f2bf(A * wv);
            }
            dw[h] = (uint32_t)e01[0] | ((uint32_t)e01[1] << 16);
        }
        *(uint4*)&wrow[(s ^ (d & 7)) << 3] = *(uint4*)dw;
    }
    ws[OFF_BIAS2 + n * DD + d] = bias2;
    ws[OFF_CORR0 + n * DD + d] = c0acc;
    ws[OFF_CORR9 + n * DD + d] = c9acc;
}

// MFMA GEMM v3: y fragments hoisted to VGPRs; yl LDS region reused as the
// z-staging tile; coalesced 16B z stores (16 store instrs/thread vs 128 u16).
__global__ __launch_bounds__(256, 2) void k_gemm(const ushort* __restrict__ yT,
                                                 const ushort* __restrict__ wT,
                                                 const float* __restrict__ ws,
                                                 ushort* __restrict__ zbuf) {
    __shared__ char smem[65536];
    ushort* yl  = (ushort*)smem;            // 32 KB (stage y)
    ushort* zst = (ushort*)smem;            // 64 x 136 ushort = 17408 B, reuses yl
    ushort* wlb[2] = { (ushort*)(smem + 32768), (ushort*)(smem + 49152) };
    int jt = blockIdx.x, n = blockIdx.y;
    int tid = threadIdx.x;
    const char* ysrc = (const char*)(yT + ((size_t)n * JPAD + jt * 128) * 128);
    const char* wsrc = (const char*)(wT + (size_t)n * DD * 128);
#pragma unroll
    for (int i = 0; i < 8; ++i)
        async_copy16(ysrc + (size_t)(i * 256 + tid) * 16, (char*)yl + (i * 256 + tid) * 16);
#pragma unroll
    for (int i = 0; i < 4; ++i)
        async_copy16(wsrc + (size_t)(i * 256 + tid) * 16, (char*)wlb[0] + (i * 256 + tid) * 16);
    __syncthreads();
    int lane = tid & 63, wid = tid >> 6;
    int wm = wid >> 1, wn = wid & 1;
    int l16 = lane & 15, g = lane >> 4;
    bool edge = (jt == 0) || (jt == 58);
    // hoist ALL y fragments to VGPRs (16 x short8 = 64 VGPR)
    short8 bfr[4][4];
#pragma unroll
    for (int ni = 0; ni < 4; ++ni)
#pragma unroll
        for (int ks = 0; ks < 4; ++ks) {
            int chunk = (ks * 4 + g) ^ (l16 & 7);
            bfr[ni][ks] = *(const short8*)&yl[(wn * 64 + ni * 16 + l16) * 128 + chunk * 8];
        }
    __syncthreads();   // all y reads done -> yl region becomes zst
#pragma unroll
    for (int dt = 0; dt < 4; ++dt) {
        if (dt < 3) {
            const char* wc = wsrc + (size_t)(dt + 1) * 16384;
#pragma unroll
            for (int i = 0; i < 4; ++i)
                async_copy16(wc + (size_t)(i * 256 + tid) * 16,
                             (char*)wlb[(dt + 1) & 1] + (i * 256 + tid) * 16);
        }
        const ushort* wcur = wlb[dt & 1];
        f32x4 acc[2][4];
#pragma unroll
        for (int a = 0; a < 2; ++a)
#pragma unroll
            for (int b = 0; b < 4; ++b) acc[a][b] = (f32x4)0.f;
#pragma unroll
        for (int ks = 0; ks < 4; ++ks) {
            short8 af[2];
            int chunk = (ks * 4 + g) ^ (l16 & 7);
#pragma unroll
            for (int mi = 0; mi < 2; ++mi)
                af[mi] = *(const short8*)&wcur[(wm * 32 + mi * 16 + l16) * 128 + chunk * 8];
#pragma unroll
            for (int mi = 0; mi < 2; ++mi)
#pragma unroll
                for (int ni = 0; ni < 4; ++ni)
                    acc[mi][ni] = __builtin_amdgcn_mfma_f32_16x16x32_bf16(af[mi], bfr[ni][ks], acc[mi][ni], 0, 0, 0);
        }
        // ---- epilogue: u16 scatter into LDS, then coalesced 16B global stores ----
#pragma unroll
        for (int mi = 0; mi < 2; ++mi) {
#pragma unroll
            for (int r = 0; r < 4; ++r) {
                int dl = wm * 32 + mi * 16 + g * 4 + r;
                int d = dt * 64 + dl;
                float bias = ws[OFF_BIAS2 + n * DD + d];
                float cr0 = 0.f, cr9 = 0.f;
                if (edge) { cr0 = ws[OFF_CORR0 + n * DD + d]; cr9 = ws[OFF_CORR9 + n * DD + d]; }
#pragma unroll
                for (int ni = 0; ni < 4; ++ni) {
                    int jl = wn * 64 + ni * 16 + l16;
                    float pre = acc[mi][ni][r] + bias;
                    if (edge) {
                        int jg = jt * 128 + jl;
                        if (jg < VV) pre -= cr0;
                        if (jg >= TV - VV) pre -= cr9;
                    }
                    zst[dl * ZSTR + jl] = f2bf(fmaxf(pre, 0.f));
                }
            }
        }
        __syncthreads();
#pragma unroll
        for (int it = 0; it < 4; ++it) {
            int idx = it * 256 + tid;
            int row = idx >> 4, q = idx & 15;
            uint4 v = *(const uint4*)&zst[row * ZSTR + q * 8];
            *(uint4*)&zbuf[((size_t)n * DD + dt * 64 + row) * JPAD + jt * 128 + q * 8] = v;
        }
        __syncthreads();
    }
}

// streaming BN2 stats: stage z row in LDS, 2-tap shifted combine, reduce.
__global__ __launch_bounds__(256) void k_bn2_stats(const ushort* __restrict__ zbuf,
                                                   const float* __restrict__ shift_out,
                                                   float* __restrict__ ws) {
    __shared__ ushort zl[JPAD];
    int d = blockIdx.x & 255;
    int n = blockIdx.x >> 8;
    int tid = threadIdx.x;
    const char* zrow = (const char*)(zbuf + ((size_t)n * DD + d) * JPAD);
    for (int k = tid; k < JPAD / 8; k += 256)
        async_copy16(zrow + (size_t)k * 16, (char*)zl + k * 16);
    __syncthreads();
    float sh = shift_out[d];
    float alpha = (sh >= 0.f) ? (1.f - sh) : (-sh);
    float beta  = (sh >= 0.f) ? sh : (1.f + sh);
    int o25 = (sh >= 0.f) ? 0 : -25;
    float s = 0.f, ss = 0.f;
    for (int jj = tid; jj < TV; jj += 256) {
        int i0 = jj + o25, i1 = jj + o25 + 25;
        float z0 = bf2f(zl[max(i0, 0)]);
        float z1 = bf2f(zl[min(i1, TV - 1)]);
        z0 = (i0 >= 0) ? z0 : 0.f;
        z1 = (i1 < TV) ? z1 : 0.f;
        float zs = alpha * z0 + beta * z1;
        s += zs;
        ss += zs * zs;
    }
    block_reduce2(s, ss);
    if (tid == 0) {
        atomicAdd(&ws[OFF_SUM2 + d], s);
        atomicAdd(&ws[OFF_SUMSQ2 + d], ss);
    }
}

// out = shifted(z)*A2 + B2; A2/B2 derived in-block from summed stats.
__global__ __launch_bounds__(256) void k_out(const ushort* __restrict__ zbuf,
                                             const float* __restrict__ shift_out,
                                             const float* __restrict__ g2,
                                             const float* __restrict__ b2,
                                             const float* __restrict__ ws,
                                             float* __restrict__ out) {
    __shared__ ushort zl[JPAD];
    int d = blockIdx.x & 255;
    int n = blockIdx.x >> 8;
    int tid = threadIdx.x;
    const char* zrow = (const char*)(zbuf + ((size_t)n * DD + d) * JPAD);
    for (int k = tid; k < JPAD / 8; k += 256)
        async_copy16(zrow + (size_t)k * 16, (char*)zl + k * 16);
    const float inv = 1.f / (float)(NN * TV);
    float m = ws[OFF_SUM2 + d] * inv;
    float var = ws[OFF_SUMSQ2 + d] * inv - m * m;
    float rstd = rsqrtf(var + 1e-5f);
    float A = rstd * g2[d];
    float B = b2[d] - m * A;
    __syncthreads();
    float sh = shift_out[d];
    float alpha = (sh >= 0.f) ? (1.f - sh) : (-sh);
    float beta  = (sh >= 0.f) ? sh : (1.f + sh);
    int o25 = (sh >= 0.f) ? 0 : -25;
    float4* orow = (float4*)(out + ((size_t)n * DD + d) * TV);
    for (int k = tid; k < TV / 4; k += 256) {
        int jj = k * 4;
        float4 o4;
        float* op = &o4.x;
#pragma unroll
        for (int q = 0; q < 4; ++q) {
            int i0 = jj + q + o25, i1 = jj + q + o25 + 25;
            float z0 = bf2f(zl[max(i0, 0)]);
            float z1 = bf2f(zl[min(i1, TV - 1)]);
            z0 = (i0 >= 0) ? z0 : 0.f;
            z1 = (i1 < TV) ? z1 : 0.f;
            op[q] = (alpha * z0 + beta * z1) * A + B;
        }
        orow[k] = o4;
    }
}

extern "C" void kernel_launch(void* const* d_in, const int* in_sizes, int n_in,
                              void* d_out, int out_size, void* d_ws, size_t ws_size,
                              hipStream_t stream) {
    const float* x        = (const float*)d_in[0];
    const int*   epoch    = (const int*)d_in[1];
    const float* bn1_g    = (const float*)d_in[2];
    const float* bn1_b    = (const float*)d_in[3];
    const float* bn2_g    = (const float*)d_in[4];
    const float* bn2_b    = (const float*)d_in[5];
    const float* shift_in = (const float*)d_in[6];
    const float* shift_out= (const float*)d_in[7];
    const float* fc1_w    = (const float*)d_in[8];
    const float* fc1_b    = (const float*)d_in[9];
    const float* fc2_w    = (const float*)d_in[10];
    const float* fc2_b    = (const float*)d_in[11];
    const float* tw       = (const float*)d_in[12];
    const float* tb       = (const float*)d_in[13];
    float* out = (float*)d_out;
    float* ws  = (float*)d_ws;
    ushort* yT = (ushort*)d_out;                    // parked in d_out until k_out
    ushort* wT = (ushort*)((char*)d_ws + WT_BYTE_OFF);
    ushort* zb = (ushort*)((char*)d_ws + Z_BYTE_OFF);

    k_zero<<<32, 256, 0, stream>>>(ws);
    k_shift_stats<<<dim3(NJT, 4, NN), 256, 0, stream>>>(x, shift_in, ws, yT);
    k_gate<<<1, 256, 0, stream>>>(bn1_g, bn1_b, fc1_w, fc1_b, fc2_w, fc2_b, shift_in, epoch, ws);
    k_wmix<<<64, 256, 0, stream>>>(tw, tb, shift_in, ws, wT);
    k_gemm<<<dim3(59, 64), 256, 0, stream>>>(yT, wT, ws, zb);
    k_bn2_stats<<<16384, 256, 0, stream>>>(zb, shift_out, ws);
    k_out<<<16384, 256, 0, stream>>>(zb, shift_out, bn2_g, bn2_b, ws, out);
}